// Round 20
// baseline (55.440 us; speedup 1.0000x reference)
//
#include <hip/hip_runtime.h>
#include <hip/hip_bf16.h>

typedef __attribute__((ext_vector_type(4))) float f32x4;
typedef __attribute__((ext_vector_type(8))) short bf16x8;

constexpr int B = 4, C = 64, N = 4096;
constexpr int KVSPLIT = 8;
constexpr int CHUNK = N / KVSPLIT;   // 512
constexpr int NQT = B * N / 16;      // 1024 q-tiles of 16 rows

__device__ __forceinline__ float bf2f(ushort u) {
    union { float f; unsigned int u32; } x;
    x.u32 = ((unsigned int)u) << 16;
    return x.f;
}
__device__ __forceinline__ ushort f2bf(float f) {
    union { float f; unsigned int u; } x;
    x.f = f;
    unsigned int r = x.u + 0x7FFFu + ((x.u >> 16) & 1u);
    return (ushort)(r >> 16);
}
// native packed convert: lo 16 = a, hi 16 = b (v_cvt_pk_bf16_f32 via compiler)
__device__ __forceinline__ uint packbf2(float a, float b) {
    union { __hip_bfloat162 h; uint u; } x;
    x.h = __float22bfloat162_rn(float2{a, b});
    return x.u;
}
__device__ __forceinline__ bf16x8 pack8(uint a, uint b, uint c, uint d) {
    union { uint u[4]; bf16x8 v; } x;
    x.u[0] = a; x.u[1] = b; x.u[2] = c; x.u[3] = d;
    return x.v;
}

#define MFMA16(a, b, c) __builtin_amdgcn_mfma_f32_16x16x32_bf16(a, b, c, 0, 0, 0)

// ---------------------------------------------------------------------------
// Kernel 1: QKV via MFMA (R10-R19-PASSED; Q scale folds log2(e) so attn can
// use native exp2 — exp2(s*log2e) == exp(s)).
// ---------------------------------------------------------------------------
__global__ __launch_bounds__(256) void qkv_kernel(
    const float* __restrict__ x, const float* __restrict__ Wq,
    const float* __restrict__ Wk, const float* __restrict__ Wv,
    ushort* __restrict__ Q, ushort* __restrict__ K, ushort* __restrict__ Vt)
{
    const int b  = blockIdx.x >> 8;
    const int n0 = (blockIdx.x & 255) << 4;
    const int lane = threadIdx.x & 63;
    const int w  = threadIdx.x >> 6;
    const int lq = lane & 15, lg = lane >> 4;

    bf16x8 bfrag[2];
#pragma unroll
    for (int kk = 0; kk < 2; ++kk) {
        float xv[8];
#pragma unroll
        for (int j = 0; j < 8; ++j)
            xv[j] = x[(size_t)(b * C + kk * 32 + lg * 8 + j) * N + n0 + lq];
        bfrag[kk] = pack8(packbf2(xv[0], xv[1]), packbf2(xv[2], xv[3]),
                          packbf2(xv[4], xv[5]), packbf2(xv[6], xv[7]));
    }

    const float* Ws[3] = {Wq, Wk, Wv};
#pragma unroll
    for (int m = 0; m < 3; ++m) {
        // 0.125 = 1/sqrt(C); 1.44269504 = log2(e) folded for attn's exp2
        const float scale = (m == 0) ? 0.125f * 1.44269504f : 1.0f;
        f32x4 acc = {0.f, 0.f, 0.f, 0.f};
#pragma unroll
        for (int kk = 0; kk < 2; ++kk) {
            const float* wp = Ws[m] + (size_t)(w * 16 + lq) * C + kk * 32 + lg * 8;
            const float4 w0 = *(const float4*)wp;
            const float4 w1 = *(const float4*)(wp + 4);
            const bf16x8 af = pack8(
                packbf2(w0.x * scale, w0.y * scale), packbf2(w0.z * scale, w0.w * scale),
                packbf2(w1.x * scale, w1.y * scale), packbf2(w1.z * scale, w1.w * scale));
            acc = MFMA16(af, bfrag[kk], acc);
        }
        if (m < 2) {   // Q/K [b][n][c]
            uint2 u;
            u.x = packbf2(acc[0], acc[1]);
            u.y = packbf2(acc[2], acc[3]);
            ushort* dst = (m == 0 ? Q : K) + ((size_t)(b * N + n0 + lq)) * C + w * 16 + 4 * lg;
            *(uint2*)dst = u;
        } else {       // Vt [b][c][n]
#pragma unroll
            for (int j = 0; j < 4; ++j)
                Vt[(size_t)(b * C + w * 16 + 4 * lg + j) * N + n0 + lq] = f2bf(acc[j]);
        }
    }
}

// ---------------------------------------------------------------------------
// Kernel 2: split-KV attention — R19-PASSED math (swapped QK^T, in-register
// P-frag, kv-permuted V staging, setprio, native exp2). Change: 2 KV-tiles
// staged per barrier (NP=8 barriers vs 16). R14's spill came from union
// ARRAYS held across the body; here ALL prefetch temps are named scalars
// (bf16x8 x2 for K; four named uint2 loads for V — no unions live).
// LDS 35.8KB -> still 4 blocks/CU.
// ---------------------------------------------------------------------------
__global__ __launch_bounds__(256, 4) void attn_kernel(
    const ushort* __restrict__ Q, const ushort* __restrict__ K,
    const ushort* __restrict__ Vt, ushort* __restrict__ pacc,
    float* __restrict__ pl)
{
    __shared__ ushort Ks[2][2][32][68];   // [buf][subtile][kvrow][c pad 68]
    __shared__ ushort Vs[2][2][64][36];   // [buf][subtile][ch][kvslot pad 36]

    const int tid  = threadIdx.x;
    const int wave = tid >> 6, lane = tid & 63;
    const int lq = lane & 15, lg = lane >> 4;
    const int qb = blockIdx.x >> 3, s = blockIdx.x & 7;   // split <-> XCD
    const int b  = qb >> 5;
    const int q0 = (qb & 31) * 128 + wave * 32;           // wave's 32 rows
    const int gqt0 = b * 256 + (qb & 31) * 8 + wave * 2;  // q-tile id of qi=0

    const ushort* Qb = Q  + ((size_t)b * N + q0) * C;
    const ushort* Kb = K  + (size_t)b * N * C + (size_t)s * CHUNK * C;
    const ushort* Vb = Vt + (size_t)b * C * N + (size_t)s * CHUNK;

    const int krow = tid >> 3, kseg = tid & 7;
    const int vrow = tid >> 2, vseg = tid & 3;
    const ushort* kgp = Kb + (size_t)krow * C + kseg * 8;
    const ushort* vgp = Vb + (size_t)vrow * N + vseg * 8;
    const int vslot0 = ((vseg & 1) << 4) + ((vseg >> 1) << 2);  // kv-permuted slot base

    bf16x8 qf[2][2];
#pragma unroll
    for (int qi = 0; qi < 2; ++qi) {
        qf[qi][0] = *(const bf16x8*)(Qb + (size_t)(qi * 16 + lq) * C + lg * 8);
        qf[qi][1] = *(const bf16x8*)(Qb + (size_t)(qi * 16 + lq) * C + 32 + lg * 8);
    }

    f32x4 acc[2][4];
#pragma unroll
    for (int qi = 0; qi < 2; ++qi)
#pragma unroll
        for (int nt = 0; nt < 4; ++nt) acc[qi][nt] = (f32x4){0.f, 0.f, 0.f, 0.f};
    float psum[2] = {0.f, 0.f};

    {   // prologue: stage tile-pair 0 (tiles 0,1) — named-scalar temps
        const bf16x8 k0 = *(const bf16x8*)kgp;
        const bf16x8 k1 = *(const bf16x8*)(kgp + (size_t)32 * C);
        const uint2 va0 = *(const uint2*)vgp;
        const uint2 vb0 = *(const uint2*)(vgp + 4);
        const uint2 va1 = *(const uint2*)(vgp + 32);
        const uint2 vb1 = *(const uint2*)(vgp + 36);
        *(bf16x8*)&Ks[0][0][krow][kseg * 8] = k0;
        *(bf16x8*)&Ks[0][1][krow][kseg * 8] = k1;
        *(uint2*)&Vs[0][0][vrow][vslot0]     = va0;
        *(uint2*)&Vs[0][0][vrow][vslot0 + 8] = vb0;
        *(uint2*)&Vs[0][1][vrow][vslot0]     = va1;
        *(uint2*)&Vs[0][1][vrow][vslot0 + 8] = vb1;
    }
    __syncthreads();

    constexpr int NP = CHUNK / 64;   // 8 pair-iterations
    for (int p = 0; p < NP; ++p) {
        const int cur = p & 1;
        bf16x8 knx0, knx1;
        uint2 vna0, vnb0, vna1, vnb1;
        if (p + 1 < NP) {   // T14: issue next pair's loads early (named scalars)
            const ushort* kpp = kgp + (size_t)(p + 1) * 64 * C;
            const ushort* vpp = vgp + (p + 1) * 64;
            knx0 = *(const bf16x8*)kpp;
            knx1 = *(const bf16x8*)(kpp + (size_t)32 * C);
            vna0 = *(const uint2*)vpp;
            vnb0 = *(const uint2*)(vpp + 4);
            vna1 = *(const uint2*)(vpp + 32);
            vnb1 = *(const uint2*)(vpp + 36);
        }

#pragma unroll
        for (int u = 0; u < 2; ++u) {   // two 32-kv subtiles per barrier
            const bf16x8 k00 = *(const bf16x8*)&Ks[cur][u][lq][lg * 8];
            const bf16x8 k01 = *(const bf16x8*)&Ks[cur][u][lq][32 + lg * 8];
            const bf16x8 k10 = *(const bf16x8*)&Ks[cur][u][16 + lq][lg * 8];
            const bf16x8 k11 = *(const bf16x8*)&Ks[cur][u][16 + lq][32 + lg * 8];
            bf16x8 vf[4];
#pragma unroll
            for (int nt = 0; nt < 4; ++nt)
                vf[nt] = *(const bf16x8*)&Vs[cur][u][nt * 16 + lq][lg * 8];

#pragma unroll
            for (int qi = 0; qi < 2; ++qi) {
                // SWAPPED QK^T: lane (lq,lg) gets S[kv=4lg+j][q=lq] (s1: +16)
                f32x4 s0 = (f32x4){0.f, 0.f, 0.f, 0.f};
                f32x4 s1 = (f32x4){0.f, 0.f, 0.f, 0.f};
                __builtin_amdgcn_s_setprio(1);
                s0 = MFMA16(k00, qf[qi][0], s0);
                s0 = MFMA16(k01, qf[qi][1], s0);
                s1 = MFMA16(k10, qf[qi][0], s1);
                s1 = MFMA16(k11, qf[qi][1], s1);
                __builtin_amdgcn_s_setprio(0);

                float p0[4], p1[4];
#pragma unroll
                for (int j = 0; j < 4; ++j) {
                    p0[j] = __builtin_amdgcn_exp2f(s0[j]);   // bare v_exp_f32
                    p1[j] = __builtin_amdgcn_exp2f(s1[j]);
                    psum[qi] += p0[j] + p1[j];
                }
                // in-register A-frag: slot 8lg+j holds kv perm = lane's own
                const bf16x8 pa = pack8(packbf2(p0[0], p0[1]), packbf2(p0[2], p0[3]),
                                        packbf2(p1[0], p1[1]), packbf2(p1[2], p1[3]));
                __builtin_amdgcn_s_setprio(1);
#pragma unroll
                for (int nt = 0; nt < 4; ++nt)
                    acc[qi][nt] = MFMA16(pa, vf[nt], acc[qi][nt]);
                __builtin_amdgcn_s_setprio(0);
            }
        }

        if (p + 1 < NP) {
            *(bf16x8*)&Ks[cur ^ 1][0][krow][kseg * 8] = knx0;
            *(bf16x8*)&Ks[cur ^ 1][1][krow][kseg * 8] = knx1;
            *(uint2*)&Vs[cur ^ 1][0][vrow][vslot0]     = vna0;
            *(uint2*)&Vs[cur ^ 1][0][vrow][vslot0 + 8] = vnb0;
            *(uint2*)&Vs[cur ^ 1][1][vrow][vslot0]     = vna1;
            *(uint2*)&Vs[cur ^ 1][1][vrow][vslot0 + 8] = vnb1;
        }
        __syncthreads();
    }

    // denominator: sum across the 4 lg groups (lanes lq, +16, +32, +48)
#pragma unroll
    for (int qi = 0; qi < 2; ++qi) {
        psum[qi] += __shfl_xor(psum[qi], 16);
        psum[qi] += __shfl_xor(psum[qi], 32);
    }

#pragma unroll
    for (int qi = 0; qi < 2; ++qi) {
        ushort* pa_out = pacc + (size_t)((gqt0 + qi) * KVSPLIT + s) * (16 * 64);
#pragma unroll
        for (int nt = 0; nt < 4; ++nt)
#pragma unroll
            for (int j = 0; j < 4; ++j)
                pa_out[(lg * 4 + j) * 64 + nt * 16 + lq] = f2bf(acc[qi][nt][j]);
        if (lane < 16)
            pl[(size_t)((gqt0 + qi) * KVSPLIT + s) * 16 + lq] = psum[qi];
    }
}

// ---------------------------------------------------------------------------
// Kernel 3: combine 8 splits + projection via MFMA + residual (R10-R19-PASSED,
// unchanged). grid = B*128 (32 tokens/blk).
// ---------------------------------------------------------------------------
__global__ __launch_bounds__(256) void proj_kernel(
    const float* __restrict__ x, const float* __restrict__ Wp,
    const ushort* __restrict__ pacc, const float* __restrict__ pl,
    float* __restrict__ out)
{
    __shared__ __attribute__((aligned(16))) ushort Hs[32][68];
    __shared__ float linv_s[32];
    const int tid = threadIdx.x;
    const int b   = blockIdx.x >> 7;
    const int n0  = (blockIdx.x & 127) << 5;
    const int qt0 = b * 256 + (n0 >> 4);     // first of 2 q-tiles (16 rows each)

    if (tid < 32) {
        const int qq = tid >> 4, row = tid & 15;
        float sm = 0.f;
#pragma unroll
        for (int s2 = 0; s2 < KVSPLIT; ++s2)
            sm += pl[(size_t)((qt0 + qq) * KVSPLIT + s2) * 16 + row];
        linv_s[tid] = 1.f / sm;
    }
    {   // combine 8 splits: thread -> (tok, 8-channel segment)
        const int tok = tid >> 3, c8 = (tid & 7) * 8;
        const ushort* base = pacc
            + ((size_t)(qt0 + (tok >> 4)) * KVSPLIT) * 1024 + (tok & 15) * 64 + c8;
        float sm[8] = {0.f, 0.f, 0.f, 0.f, 0.f, 0.f, 0.f, 0.f};
#pragma unroll
        for (int s2 = 0; s2 < KVSPLIT; ++s2) {
            union { bf16x8 v; ushort u[8]; } pk;
            pk.v = *(const bf16x8*)(base + s2 * 1024);
#pragma unroll
            for (int j = 0; j < 8; ++j) sm[j] += bf2f(pk.u[j]);
        }
        *(bf16x8*)&Hs[tok][c8] = pack8(
            packbf2(sm[0], sm[1]), packbf2(sm[2], sm[3]),
            packbf2(sm[4], sm[5]), packbf2(sm[6], sm[7]));
    }
    __syncthreads();

    const int lane = tid & 63, w = tid >> 6;
    const int lq = lane & 15, lg = lane >> 4;

    bf16x8 af[2];
#pragma unroll
    for (int kk = 0; kk < 2; ++kk) {
        const float* wp = Wp + (size_t)(w * 16 + lq) * C + kk * 32 + lg * 8;
        const float4 w0 = *(const float4*)wp;
        const float4 w1 = *(const float4*)(wp + 4);
        af[kk] = pack8(packbf2(w0.x, w0.y), packbf2(w0.z, w0.w),
                       packbf2(w1.x, w1.y), packbf2(w1.z, w1.w));
    }

#pragma unroll
    for (int th = 0; th < 2; ++th) {          // two 16-token D tiles
        f32x4 acc = {0.f, 0.f, 0.f, 0.f};
#pragma unroll
        for (int kk = 0; kk < 2; ++kk) {
            const bf16x8 bf = *(const bf16x8*)&Hs[th * 16 + lq][kk * 32 + lg * 8];
            acc = MFMA16(af[kk], bf, acc);
        }
        const float li = linv_s[th * 16 + lq];
#pragma unroll
        for (int j = 0; j < 4; ++j) {
            const int o = w * 16 + 4 * lg + j;
            const size_t idx = (size_t)(b * C + o) * N + n0 + th * 16 + lq;
            out[idx] = x[idx] + acc[j] * li;
        }
    }
}

// ---------------------------------------------------------------------------
extern "C" void kernel_launch(void* const* d_in, const int* in_sizes, int n_in,
                              void* d_out, int out_size, void* d_ws, size_t ws_size,
                              hipStream_t stream)
{
    const float* x  = (const float*)d_in[0];
    const float* Wq = (const float*)d_in[1];
    const float* Wk = (const float*)d_in[2];
    const float* Wv = (const float*)d_in[3];
    const float* Wp = (const float*)d_in[4];
    float* out = (float*)d_out;

    // workspace: Q,K,Vt bf16 2MB each + pacc bf16 16.8MB + pl 0.5MB = 23.3MB
    ushort* Q    = (ushort*)d_ws;
    ushort* K    = Q  + (size_t)B * N * C;
    ushort* Vt   = K  + (size_t)B * N * C;
    ushort* pacc = Vt + (size_t)B * N * C;
    float*  pl   = (float*)(pacc + (size_t)NQT * KVSPLIT * 16 * 64);

    qkv_kernel<<<B * 256, 256, 0, stream>>>(x, Wq, Wk, Wv, Q, K, Vt);
    attn_kernel<<<128 * KVSPLIT, 256, 0, stream>>>(Q, K, Vt, pacc, pl);
    proj_kernel<<<B * 128, 256, 0, stream>>>(x, Wp, pacc, pl, out);
}

// Round 21
// 44.352 us; speedup vs baseline: 1.2500x; 1.2500x over previous
//
#include <hip/hip_runtime.h>
#include <hip/hip_bf16.h>

typedef __attribute__((ext_vector_type(4))) float f32x4;
typedef __attribute__((ext_vector_type(8))) short bf16x8;

constexpr int B = 4, C = 64, N = 4096;
constexpr int KVSPLIT = 8;
constexpr int CHUNK = N / KVSPLIT;   // 512
constexpr int NQT = B * N / 16;      // 1024 q-tiles of 16 rows

__device__ __forceinline__ float bf2f(ushort u) {
    union { float f; unsigned int u32; } x;
    x.u32 = ((unsigned int)u) << 16;
    return x.f;
}
__device__ __forceinline__ ushort f2bf(float f) {
    union { float f; unsigned int u; } x;
    x.f = f;
    unsigned int r = x.u + 0x7FFFu + ((x.u >> 16) & 1u);
    return (ushort)(r >> 16);
}
// native packed convert: lo 16 = a, hi 16 = b (v_cvt_pk_bf16_f32 via compiler)
__device__ __forceinline__ uint packbf2(float a, float b) {
    union { __hip_bfloat162 h; uint u; } x;
    x.h = __float22bfloat162_rn(float2{a, b});
    return x.u;
}
__device__ __forceinline__ bf16x8 pack8(uint a, uint b, uint c, uint d) {
    union { uint u[4]; bf16x8 v; } x;
    x.u[0] = a; x.u[1] = b; x.u[2] = c; x.u[3] = d;
    return x.v;
}

#define MFMA16(a, b, c) __builtin_amdgcn_mfma_f32_16x16x32_bf16(a, b, c, 0, 0, 0)

// ---------------------------------------------------------------------------
// Kernel 1: QKV via MFMA (R10-R19-PASSED; Q scale folds log2(e) so attn can
// use native exp2 — exp2(s*log2e) == exp(s)).
// ---------------------------------------------------------------------------
__global__ __launch_bounds__(256) void qkv_kernel(
    const float* __restrict__ x, const float* __restrict__ Wq,
    const float* __restrict__ Wk, const float* __restrict__ Wv,
    ushort* __restrict__ Q, ushort* __restrict__ K, ushort* __restrict__ Vt)
{
    const int b  = blockIdx.x >> 8;
    const int n0 = (blockIdx.x & 255) << 4;
    const int lane = threadIdx.x & 63;
    const int w  = threadIdx.x >> 6;
    const int lq = lane & 15, lg = lane >> 4;

    bf16x8 bfrag[2];
#pragma unroll
    for (int kk = 0; kk < 2; ++kk) {
        float xv[8];
#pragma unroll
        for (int j = 0; j < 8; ++j)
            xv[j] = x[(size_t)(b * C + kk * 32 + lg * 8 + j) * N + n0 + lq];
        bfrag[kk] = pack8(packbf2(xv[0], xv[1]), packbf2(xv[2], xv[3]),
                          packbf2(xv[4], xv[5]), packbf2(xv[6], xv[7]));
    }

    const float* Ws[3] = {Wq, Wk, Wv};
#pragma unroll
    for (int m = 0; m < 3; ++m) {
        // 0.125 = 1/sqrt(C); 1.44269504 = log2(e) folded for attn's exp2
        const float scale = (m == 0) ? 0.125f * 1.44269504f : 1.0f;
        f32x4 acc = {0.f, 0.f, 0.f, 0.f};
#pragma unroll
        for (int kk = 0; kk < 2; ++kk) {
            const float* wp = Ws[m] + (size_t)(w * 16 + lq) * C + kk * 32 + lg * 8;
            const float4 w0 = *(const float4*)wp;
            const float4 w1 = *(const float4*)(wp + 4);
            const bf16x8 af = pack8(
                packbf2(w0.x * scale, w0.y * scale), packbf2(w0.z * scale, w0.w * scale),
                packbf2(w1.x * scale, w1.y * scale), packbf2(w1.z * scale, w1.w * scale));
            acc = MFMA16(af, bfrag[kk], acc);
        }
        if (m < 2) {   // Q/K [b][n][c]
            uint2 u;
            u.x = packbf2(acc[0], acc[1]);
            u.y = packbf2(acc[2], acc[3]);
            ushort* dst = (m == 0 ? Q : K) + ((size_t)(b * N + n0 + lq)) * C + w * 16 + 4 * lg;
            *(uint2*)dst = u;
        } else {       // Vt [b][c][n]
#pragma unroll
            for (int j = 0; j < 4; ++j)
                Vt[(size_t)(b * C + w * 16 + 4 * lg + j) * N + n0 + lq] = f2bf(acc[j]);
        }
    }
}

// ---------------------------------------------------------------------------
// Kernel 2: split-KV attention — R19-PASSED KERNEL, byte-identical revert.
// Swapped QK^T (lane owns P[q=lq][kv]), in-register P-frag via kv-permuted
// V staging, double-buffered 1-tile-per-barrier staging, setprio, native
// exp2 (__builtin_amdgcn_exp2f; log2e pre-folded into Q scale).
// R14/R20 both refuted 2-tiles-per-barrier: prefetch temps across the
// doubled compute body spill to scratch (WRITE_SIZE 69-95MB) at 4 blk/CU.
// ---------------------------------------------------------------------------
__global__ __launch_bounds__(256, 4) void attn_kernel(
    const ushort* __restrict__ Q, const ushort* __restrict__ K,
    const ushort* __restrict__ Vt, ushort* __restrict__ pacc,
    float* __restrict__ pl)
{
    __shared__ ushort Ks[2][32][68];                              // 136B rows
    __shared__ ushort Vs[2][64][36];                              // 72B rows

    const int tid  = threadIdx.x;
    const int wave = tid >> 6, lane = tid & 63;
    const int lq = lane & 15, lg = lane >> 4;
    const int qb = blockIdx.x >> 3, s = blockIdx.x & 7;   // split <-> XCD
    const int b  = qb >> 5;
    const int q0 = (qb & 31) * 128 + wave * 32;           // wave's 32 rows
    const int gqt0 = b * 256 + (qb & 31) * 8 + wave * 2;  // q-tile id of qi=0

    const ushort* Qb = Q  + ((size_t)b * N + q0) * C;
    const ushort* Kb = K  + (size_t)b * N * C + (size_t)s * CHUNK * C;
    const ushort* Vb = Vt + (size_t)b * C * N + (size_t)s * CHUNK;

    const int krow = tid >> 3, kseg = tid & 7;
    const int vrow = tid >> 2, vseg = tid & 3;
    const ushort* kgp = Kb + (size_t)krow * C + kseg * 8;
    const ushort* vgp = Vb + (size_t)vrow * N + vseg * 8;
    const int vslot0 = ((vseg & 1) << 4) + ((vseg >> 1) << 2);  // kv-permuted slot base

    bf16x8 qf[2][2];
#pragma unroll
    for (int qi = 0; qi < 2; ++qi) {
        qf[qi][0] = *(const bf16x8*)(Qb + (size_t)(qi * 16 + lq) * C + lg * 8);
        qf[qi][1] = *(const bf16x8*)(Qb + (size_t)(qi * 16 + lq) * C + 32 + lg * 8);
    }

    f32x4 acc[2][4];
#pragma unroll
    for (int qi = 0; qi < 2; ++qi)
#pragma unroll
        for (int nt = 0; nt < 4; ++nt) acc[qi][nt] = (f32x4){0.f, 0.f, 0.f, 0.f};
    float psum[2] = {0.f, 0.f};

    {   // prologue: stage tile 0 (V kv-permuted)
        bf16x8 kv = *(const bf16x8*)kgp;
        union { bf16x8 v; uint2 h[2]; } vv;
        vv.v = *(const bf16x8*)vgp;
        *(bf16x8*)&Ks[0][krow][kseg * 8] = kv;
        *(uint2*)&Vs[0][vrow][vslot0]     = vv.h[0];   // kv i=0..3
        *(uint2*)&Vs[0][vrow][vslot0 + 8] = vv.h[1];   // kv i=4..7
    }
    __syncthreads();

    constexpr int NT = CHUNK / 32;   // 16 tiles
    for (int t = 0; t < NT; ++t) {
        const int cur = t & 1;
        bf16x8 knx;
        union { bf16x8 v; uint2 h[2]; } vnx;
        if (t + 1 < NT) {   // T14: issue next tile's loads early
            knx = *(const bf16x8*)(kgp + (size_t)(t + 1) * 32 * C);
            vnx.v = *(const bf16x8*)(vgp + (t + 1) * 32);
        }

        // shared fragment reads: once per tile, used by BOTH q-tiles
        const bf16x8 k00 = *(const bf16x8*)&Ks[cur][lq][lg * 8];
        const bf16x8 k01 = *(const bf16x8*)&Ks[cur][lq][32 + lg * 8];
        const bf16x8 k10 = *(const bf16x8*)&Ks[cur][16 + lq][lg * 8];
        const bf16x8 k11 = *(const bf16x8*)&Ks[cur][16 + lq][32 + lg * 8];
        bf16x8 vf[4];
#pragma unroll
        for (int nt = 0; nt < 4; ++nt)
            vf[nt] = *(const bf16x8*)&Vs[cur][nt * 16 + lq][lg * 8];

#pragma unroll
        for (int qi = 0; qi < 2; ++qi) {
            // SWAPPED QK^T: lane (lq,lg) gets S[kv=4lg+j][q=lq] (s1: kv+16)
            f32x4 s0 = (f32x4){0.f, 0.f, 0.f, 0.f};
            f32x4 s1 = (f32x4){0.f, 0.f, 0.f, 0.f};
            __builtin_amdgcn_s_setprio(1);
            s0 = MFMA16(k00, qf[qi][0], s0);
            s0 = MFMA16(k01, qf[qi][1], s0);
            s1 = MFMA16(k10, qf[qi][0], s1);
            s1 = MFMA16(k11, qf[qi][1], s1);
            __builtin_amdgcn_s_setprio(0);

            float p0[4], p1[4];
#pragma unroll
            for (int j = 0; j < 4; ++j) {
                p0[j] = __builtin_amdgcn_exp2f(s0[j]);   // bare v_exp_f32
                p1[j] = __builtin_amdgcn_exp2f(s1[j]);
                psum[qi] += p0[j] + p1[j];
            }
            // in-register A-frag: slot 8lg+j holds kv perm(8lg+j) = lane's own
            const bf16x8 pa = pack8(packbf2(p0[0], p0[1]), packbf2(p0[2], p0[3]),
                                    packbf2(p1[0], p1[1]), packbf2(p1[2], p1[3]));
            __builtin_amdgcn_s_setprio(1);
#pragma unroll
            for (int nt = 0; nt < 4; ++nt)
                acc[qi][nt] = MFMA16(pa, vf[nt], acc[qi][nt]);
            __builtin_amdgcn_s_setprio(0);
        }

        if (t + 1 < NT) {
            *(bf16x8*)&Ks[cur ^ 1][krow][kseg * 8] = knx;
            *(uint2*)&Vs[cur ^ 1][vrow][vslot0]     = vnx.h[0];
            *(uint2*)&Vs[cur ^ 1][vrow][vslot0 + 8] = vnx.h[1];
        }
        __syncthreads();
    }

    // denominator: sum across the 4 lg groups (lanes lq, +16, +32, +48)
#pragma unroll
    for (int qi = 0; qi < 2; ++qi) {
        psum[qi] += __shfl_xor(psum[qi], 16);
        psum[qi] += __shfl_xor(psum[qi], 32);
    }

#pragma unroll
    for (int qi = 0; qi < 2; ++qi) {
        ushort* pa_out = pacc + (size_t)((gqt0 + qi) * KVSPLIT + s) * (16 * 64);
#pragma unroll
        for (int nt = 0; nt < 4; ++nt)
#pragma unroll
            for (int j = 0; j < 4; ++j)
                pa_out[(lg * 4 + j) * 64 + nt * 16 + lq] = f2bf(acc[qi][nt][j]);
        if (lane < 16)
            pl[(size_t)((gqt0 + qi) * KVSPLIT + s) * 16 + lq] = psum[qi];
    }
}

// ---------------------------------------------------------------------------
// Kernel 3: combine 8 splits + projection via MFMA + residual (R10-R19-PASSED,
// unchanged). grid = B*128 (32 tokens/blk).
// ---------------------------------------------------------------------------
__global__ __launch_bounds__(256) void proj_kernel(
    const float* __restrict__ x, const float* __restrict__ Wp,
    const ushort* __restrict__ pacc, const float* __restrict__ pl,
    float* __restrict__ out)
{
    __shared__ __attribute__((aligned(16))) ushort Hs[32][68];
    __shared__ float linv_s[32];
    const int tid = threadIdx.x;
    const int b   = blockIdx.x >> 7;
    const int n0  = (blockIdx.x & 127) << 5;
    const int qt0 = b * 256 + (n0 >> 4);     // first of 2 q-tiles (16 rows each)

    if (tid < 32) {
        const int qq = tid >> 4, row = tid & 15;
        float sm = 0.f;
#pragma unroll
        for (int s2 = 0; s2 < KVSPLIT; ++s2)
            sm += pl[(size_t)((qt0 + qq) * KVSPLIT + s2) * 16 + row];
        linv_s[tid] = 1.f / sm;
    }
    {   // combine 8 splits: thread -> (tok, 8-channel segment)
        const int tok = tid >> 3, c8 = (tid & 7) * 8;
        const ushort* base = pacc
            + ((size_t)(qt0 + (tok >> 4)) * KVSPLIT) * 1024 + (tok & 15) * 64 + c8;
        float sm[8] = {0.f, 0.f, 0.f, 0.f, 0.f, 0.f, 0.f, 0.f};
#pragma unroll
        for (int s2 = 0; s2 < KVSPLIT; ++s2) {
            union { bf16x8 v; ushort u[8]; } pk;
            pk.v = *(const bf16x8*)(base + s2 * 1024);
#pragma unroll
            for (int j = 0; j < 8; ++j) sm[j] += bf2f(pk.u[j]);
        }
        *(bf16x8*)&Hs[tok][c8] = pack8(
            packbf2(sm[0], sm[1]), packbf2(sm[2], sm[3]),
            packbf2(sm[4], sm[5]), packbf2(sm[6], sm[7]));
    }
    __syncthreads();

    const int lane = tid & 63, w = tid >> 6;
    const int lq = lane & 15, lg = lane >> 4;

    bf16x8 af[2];
#pragma unroll
    for (int kk = 0; kk < 2; ++kk) {
        const float* wp = Wp + (size_t)(w * 16 + lq) * C + kk * 32 + lg * 8;
        const float4 w0 = *(const float4*)wp;
        const float4 w1 = *(const float4*)(wp + 4);
        af[kk] = pack8(packbf2(w0.x, w0.y), packbf2(w0.z, w0.w),
                       packbf2(w1.x, w1.y), packbf2(w1.z, w1.w));
    }

#pragma unroll
    for (int th = 0; th < 2; ++th) {          // two 16-token D tiles
        f32x4 acc = {0.f, 0.f, 0.f, 0.f};
#pragma unroll
        for (int kk = 0; kk < 2; ++kk) {
            const bf16x8 bf = *(const bf16x8*)&Hs[th * 16 + lq][kk * 32 + lg * 8];
            acc = MFMA16(af[kk], bf, acc);
        }
        const float li = linv_s[th * 16 + lq];
#pragma unroll
        for (int j = 0; j < 4; ++j) {
            const int o = w * 16 + 4 * lg + j;
            const size_t idx = (size_t)(b * C + o) * N + n0 + th * 16 + lq;
            out[idx] = x[idx] + acc[j] * li;
        }
    }
}

// ---------------------------------------------------------------------------
extern "C" void kernel_launch(void* const* d_in, const int* in_sizes, int n_in,
                              void* d_out, int out_size, void* d_ws, size_t ws_size,
                              hipStream_t stream)
{
    const float* x  = (const float*)d_in[0];
    const float* Wq = (const float*)d_in[1];
    const float* Wk = (const float*)d_in[2];
    const float* Wv = (const float*)d_in[3];
    const float* Wp = (const float*)d_in[4];
    float* out = (float*)d_out;

    // workspace: Q,K,Vt bf16 2MB each + pacc bf16 16.8MB + pl 0.5MB = 23.3MB
    ushort* Q    = (ushort*)d_ws;
    ushort* K    = Q  + (size_t)B * N * C;
    ushort* Vt   = K  + (size_t)B * N * C;
    ushort* pacc = Vt + (size_t)B * N * C;
    float*  pl   = (float*)(pacc + (size_t)NQT * KVSPLIT * 16 * 64);

    qkv_kernel<<<B * 256, 256, 0, stream>>>(x, Wq, Wk, Wv, Q, K, Vt);
    attn_kernel<<<128 * KVSPLIT, 256, 0, stream>>>(Q, K, Vt, pacc, pl);
    proj_kernel<<<B * 128, 256, 0, stream>>>(x, Wp, pacc, pl, out);
}